// Round 3
// baseline (243.179 us; speedup 1.0000x reference)
//
#include <hip/hip_runtime.h>
#include <math.h>

// Problem constants (from reference): N=100000, S=64, Q=50, P=3
#define N_Q 50
#define N_P 3
#define N_S 64
#define ROW 150      // Q*P floats per pauli word
#define ROWP 153     // LDS-padded row (odd stride -> <=2-way bank alias, free)
#define BLK_N 64     // n-rows per block
#define THREADS 256  // 4 waves; wave w handles s in [16w, 16w+16)
#define SCHUNK 16

// ws layout (bytes):
//   [0      .. 12504)   partials double[1563]
//   [12544  .. +4)      done-counter int (zeroed by precompute each launch)
//   [12608  .. +38400)  HP   float[Q][S][3]  normalized heads, q-major
//   [51008  .. +256)    hrv  float[S]        smoothed head ratios
#define WS_CNT_OFF 12544
#define WS_HP_OFF 12608
#define WS_HRV_OFF 51008

__device__ __forceinline__ float softplus20(float x) {
    float z = x * 20.0f;
    return fmaxf(z, 0.0f) + log1pf(expf(-fabsf(z)));  // stable softplus
}

__global__ void precompute_kernel(const float* __restrict__ heads_param,
                                  const float* __restrict__ hr_param,
                                  float* __restrict__ HP,
                                  float* __restrict__ hrv,
                                  int* __restrict__ cnt) {
    const int tid = threadIdx.x;

    if (blockIdx.x == 0) {
        if (tid == 0) *cnt = 0;  // ws is re-poisoned every launch
        // head ratios: one wave (S == 64)
        if (tid < N_S) {
            float sp = softplus20(hr_param[tid]);
            float tot = sp;
            #pragma unroll
            for (int off = 32; off; off >>= 1) tot += __shfl_xor(tot, off);
            float hr = sp / fmaxf(tot, 1e-12f);
            hrv[tid] = (hr + 0.001f / (float)N_S) / 1.001f;
        }
    }

    // heads: S*Q = 3200 cells spread over the grid. EXACT reference semantics:
    // h_p = sp_p / max(sum, EPS) — when the EPS clamp fires the row does NOT
    // sum to 1, so all three components are stored.
    int idx = blockIdx.x * blockDim.x + tid;
    if (idx < N_S * N_Q) {
        int q = idx / N_S;
        int s = idx - q * N_S;
        const float* hp = heads_param + ((size_t)s * N_Q + q) * N_P;
        float sp0 = softplus20(hp[0]);
        float sp1 = softplus20(hp[1]);
        float sp2 = softplus20(hp[2]);
        float denom = fmaxf(sp0 + sp1 + sp2, 1e-12f);
        float* o = HP + ((size_t)q * N_S + s) * 3;
        o[0] = sp0 / denom;
        o[1] = sp1 / denom;
        o[2] = sp2 / denom;
    }
}

// 48 floats (16 s-values x 3 comps) of H for one q, as 12 float4 registers.
__device__ __forceinline__ void loadH(float4 (&B)[12], const float4* __restrict__ p) {
    #pragma unroll
    for (int j = 0; j < 12; ++j) B[j] = p[j];
}

__device__ __forceinline__ void computeQ(const float4 (&B)[12],
                                         float a0, float a1, float a2,
                                         float (&p)[SCHUNK]) {
    #pragma unroll
    for (int g = 0; g < 4; ++g) {
        float4 b0 = B[3 * g], b1 = B[3 * g + 1], b2 = B[3 * g + 2];
        p[4 * g + 0] *= fmaf(b0.x, a0, fmaf(b0.y, a1, b0.z * a2));
        p[4 * g + 1] *= fmaf(b0.w, a0, fmaf(b1.x, a1, b1.y * a2));
        p[4 * g + 2] *= fmaf(b1.z, a0, fmaf(b1.w, a1, b2.x * a2));
        p[4 * g + 3] *= fmaf(b2.y, a0, fmaf(b2.z, a1, b2.w * a2));
    }
}

__global__ __launch_bounds__(THREADS) void main_kernel(
    const float* __restrict__ A, const float* __restrict__ coeff,
    const float* __restrict__ HP, const float* __restrict__ hrv,
    double* __restrict__ partials, int* __restrict__ cnt,
    float* __restrict__ out, int N) {
    __shared__ float Atile[BLK_N * ROWP];   // 39168 B
    __shared__ float covs[4][BLK_N];
    __shared__ int isLast;

    const int tid = threadIdx.x;
    const int lane = tid & 63;
    const int wave = tid >> 6;
    const int nbase = blockIdx.x * BLK_N;

    // --- stage A tile (64 rows x 150 floats), coalesced float2 loads ---
    {
        const int nelem2 = BLK_N * (ROW / 2);  // 4800
        for (int i = tid; i < nelem2; i += THREADS) {
            int row = i / (ROW / 2);
            int col2 = i - row * (ROW / 2);
            int n = nbase + row;
            if (n >= N) n = N - 1;  // clamp: duplicate row, masked in epilogue
            const float2 v = *(const float2*)(A + (size_t)n * ROW + col2 * 2);
            const int la = row * ROWP + col2 * 2;
            Atile[la + 0] = v.x;
            Atile[la + 1] = v.y;
        }
    }
    __syncthreads();

    // NOTE: no readfirstlane here — keep the H address divergent-typed so the
    // compiler emits VECTOR global loads (vmcnt domain, L1 broadcast), not
    // s_load (SMEM thrashes K$ and serializes on shared lgkmcnt with ds_read).
    const int s0 = wave * SCHUNK;
    const float4* __restrict__ Hbase =
        (const float4*)HP + (size_t)wave * 12;  // float offset s0*3 = 48*wave

    float prod[SCHUNK];
    #pragma unroll
    for (int i = 0; i < SCHUNK; ++i) prod[i] = 1.0f;

    const float* Arow = Atile + lane * ROWP;

    float4 B0[12], B1[12];
    loadH(B0, Hbase);  // q = 0

    for (int q = 0; q < N_Q; q += 2) {
        loadH(B1, Hbase + (size_t)(q + 1) * 48);        // prefetch q+1
        float a0 = Arow[3 * q + 0];
        float a1 = Arow[3 * q + 1];
        float a2 = Arow[3 * q + 2];
        computeQ(B0, a0, a1, a2, prod);
        int qn = q + 2;
        if (qn >= N_Q) qn = 0;                          // wrap: valid dummy load
        loadH(B0, Hbase + (size_t)qn * 48);             // prefetch q+2
        float c0 = Arow[3 * q + 3];
        float c1 = Arow[3 * q + 4];
        float c2 = Arow[3 * q + 5];
        computeQ(B1, c0, c1, c2, prod);
    }

    // ratio-weighted partial sum over this wave's s-chunk
    float acc = 0.0f;
    #pragma unroll
    for (int i = 0; i < SCHUNK; ++i) acc = fmaf(hrv[s0 + i], prod[i], acc);

    covs[wave][lane] = acc;
    __syncthreads();

    if (wave == 0) {
        const int n = nbase + lane;
        float cov = covs[0][lane] + covs[1][lane] + covs[2][lane] + covs[3][lane];
        float term = 0.0f;
        if (n < N) {
            float c = coeff[n];
            term = (c * c) / cov;
        }
        double td = (double)term;
        #pragma unroll
        for (int off = 32; off; off >>= 1) td += __shfl_down(td, off);
        if (lane == 0) {
            partials[blockIdx.x] = td;
            __threadfence();                 // release partial
            int v = atomicAdd(cnt, 1);
            isLast = (v == (int)gridDim.x - 1);
        }
    }
    __syncthreads();

    // last-finishing block reduces all partials
    if (isLast) {
        __threadfence();                     // acquire
        double s = 0.0;
        for (int i = tid; i < (int)gridDim.x; i += THREADS) s += partials[i];
        #pragma unroll
        for (int off = 32; off; off >>= 1) s += __shfl_down(s, off);
        __shared__ double red[4];
        if (lane == 0) red[wave] = s;
        __syncthreads();
        if (tid == 0) out[0] = (float)(red[0] + red[1] + red[2] + red[3]);
    }
}

extern "C" void kernel_launch(void* const* d_in, const int* in_sizes, int n_in,
                              void* d_out, int out_size, void* d_ws, size_t ws_size,
                              hipStream_t stream) {
    const float* A           = (const float*)d_in[0];  // [N, Q, P]
    const float* coeff       = (const float*)d_in[1];  // [N]
    const float* heads_param = (const float*)d_in[2];  // [S, Q, P]
    const float* hr_param    = (const float*)d_in[3];  // [S]
    const int N = in_sizes[1];
    const int nblocks = (N + BLK_N - 1) / BLK_N;

    char* ws = (char*)d_ws;
    double* partials = (double*)ws;
    int*   cnt = (int*)(ws + WS_CNT_OFF);
    float* HP  = (float*)(ws + WS_HP_OFF);
    float* hrv = (float*)(ws + WS_HRV_OFF);
    float* out = (float*)d_out;

    const int pre_blocks = (N_S * N_Q + THREADS - 1) / THREADS;  // 13
    precompute_kernel<<<pre_blocks, THREADS, 0, stream>>>(heads_param, hr_param,
                                                          HP, hrv, cnt);
    main_kernel<<<nblocks, THREADS, 0, stream>>>(A, coeff, HP, hrv, partials,
                                                 cnt, out, N);
}

// Round 4
// 152.151 us; speedup vs baseline: 1.5983x; 1.5983x over previous
//
#include <hip/hip_runtime.h>
#include <math.h>

// Problem constants (from reference): N=100000, S=64, Q=50, P=3
#define N_Q 50
#define N_P 3
#define N_S 64
#define ROW 150        // Q*P floats per pauli word
#define BLK_ROWS 128   // rows per block (2 per lane)
#define THREADS 256    // 4 waves; wave w handles s in [16w, 16w+16)
#define SCHUNK 16

// ws layout (bytes):
//   [0      .. 6256)    partials double[782]
//   [6272   .. +4)      done-counter int (zeroed by precompute each launch)
//   [6336   .. +38400)  HP   float[Q][S][3]  normalized heads, q-major
//   [44736  .. +256)    hrv  float[S]        smoothed head ratios
#define WS_CNT_OFF 6272
#define WS_HP_OFF 6336
#define WS_HRV_OFF 44736

__device__ __forceinline__ float softplus20(float x) {
    float z = x * 20.0f;
    return fmaxf(z, 0.0f) + log1pf(expf(-fabsf(z)));  // stable softplus
}

__global__ void precompute_kernel(const float* __restrict__ heads_param,
                                  const float* __restrict__ hr_param,
                                  float* __restrict__ HP,
                                  float* __restrict__ hrv,
                                  int* __restrict__ cnt) {
    const int tid = threadIdx.x;
    if (blockIdx.x == 0) {
        if (tid == 0) *cnt = 0;  // ws is re-poisoned every launch
        if (tid < N_S) {
            float sp = softplus20(hr_param[tid]);
            float tot = sp;
            #pragma unroll
            for (int off = 32; off; off >>= 1) tot += __shfl_xor(tot, off);
            float hr = sp / fmaxf(tot, 1e-12f);
            hrv[tid] = (hr + 0.001f / (float)N_S) / 1.001f;
        }
    }
    // EXACT reference semantics: h_p = sp_p / max(sum, EPS); when the clamp
    // fires the row does NOT sum to 1, so all three components are stored.
    int idx = blockIdx.x * blockDim.x + tid;
    if (idx < N_S * N_Q) {
        int q = idx / N_S;
        int s = idx - q * N_S;
        const float* hp = heads_param + ((size_t)s * N_Q + q) * N_P;
        float sp0 = softplus20(hp[0]);
        float sp1 = softplus20(hp[1]);
        float sp2 = softplus20(hp[2]);
        float denom = fmaxf(sp0 + sp1 + sp2, 1e-12f);
        float* o = HP + ((size_t)q * N_S + s) * 3;
        o[0] = sp0 / denom;
        o[1] = sp1 / denom;
        o[2] = sp2 / denom;
    }
}

// One q, 16 s-values (4 groups of 4), applied to TWO rows sharing the H regs.
__device__ __forceinline__ void computeQ2(const float4* __restrict__ Hq,
                                          float a0, float a1, float a2,
                                          float c0, float c1, float c2,
                                          float (&p)[SCHUNK], float (&p2)[SCHUNK]) {
    #pragma unroll
    for (int g = 0; g < 4; ++g) {
        float4 b0 = Hq[3 * g], b1 = Hq[3 * g + 1], b2 = Hq[3 * g + 2];
        // layout per 4 s: [h00 h01 h02 h10][h11 h12 h20 h21][h22 h30 h31 h32]
        p [4*g+0] *= fmaf(b0.x, a0, fmaf(b0.y, a1, b0.z * a2));
        p2[4*g+0] *= fmaf(b0.x, c0, fmaf(b0.y, c1, b0.z * c2));
        p [4*g+1] *= fmaf(b0.w, a0, fmaf(b1.x, a1, b1.y * a2));
        p2[4*g+1] *= fmaf(b0.w, c0, fmaf(b1.x, c1, b1.y * c2));
        p [4*g+2] *= fmaf(b1.z, a0, fmaf(b1.w, a1, b2.x * a2));
        p2[4*g+2] *= fmaf(b1.z, c0, fmaf(b1.w, c1, b2.x * c2));
        p [4*g+3] *= fmaf(b2.y, a0, fmaf(b2.z, a1, b2.w * a2));
        p2[4*g+3] *= fmaf(b2.y, c0, fmaf(b2.z, c1, b2.w * c2));
    }
}

__global__ __launch_bounds__(THREADS) void main_kernel(
    const float* __restrict__ A, const float* __restrict__ coeff,
    const float* __restrict__ HP, const float* __restrict__ hrv,
    double* __restrict__ partials, int* __restrict__ cnt,
    float* __restrict__ out, int N) {
    __shared__ float hHs[N_Q * N_S * 3];     // 38400 B, q-major
    __shared__ float hrvl[N_S];
    __shared__ float covs[4][BLK_ROWS];      // 2048 B
    __shared__ double redd[2];
    __shared__ int isLast;

    const int tid = threadIdx.x;
    const int lane = tid & 63;
    const int wave = tid >> 6;
    const int nbase = blockIdx.x * BLK_ROWS;

    // --- stage H (+hrv) into LDS once per block, coalesced float4 ---
    for (int i = tid; i < (N_Q * N_S * 3) / 4; i += THREADS)
        ((float4*)hHs)[i] = ((const float4*)HP)[i];
    if (tid < N_S) hrvl[tid] = hrv[tid];
    __syncthreads();

    // lane owns rows n0 = nbase+lane and n1 = nbase+64+lane
    int n0 = nbase + lane;        if (n0 >= N) n0 = N - 1;
    int n1 = nbase + 64 + lane;   if (n1 >= N) n1 = N - 1;
    const float2* __restrict__ pA0 = (const float2*)A + (size_t)n0 * (ROW / 2);
    const float2* __restrict__ pA1 = (const float2*)A + (size_t)n1 * (ROW / 2);

    float prod0[SCHUNK], prod1[SCHUNK];
    #pragma unroll
    for (int i = 0; i < SCHUNK; ++i) { prod0[i] = 1.0f; prod1[i] = 1.0f; }

    // H base for this wave's s-chunk: float4 index 96*w_window + 12*wave
    const float4* __restrict__ Hbase = (const float4*)hHs + 12 * wave;

    #pragma unroll 5
    for (int w = 0; w < N_Q / 2; ++w) {   // window = 2 q = 6 floats/row
        float2 x0 = pA0[3 * w + 0], x1 = pA0[3 * w + 1], x2 = pA0[3 * w + 2];
        float2 y0 = pA1[3 * w + 0], y1 = pA1[3 * w + 1], y2 = pA1[3 * w + 2];
        const float4* Hq = Hbase + 96 * w;      // q = 2w
        computeQ2(Hq,      x0.x, x0.y, x1.x,  y0.x, y0.y, y1.x, prod0, prod1);
        computeQ2(Hq + 48, x1.y, x2.x, x2.y,  y1.y, y2.x, y2.y, prod0, prod1);
    }

    // ratio-weighted partials for both rows
    float acc0 = 0.0f, acc1 = 0.0f;
    const int s0 = wave * SCHUNK;
    #pragma unroll
    for (int i = 0; i < SCHUNK; ++i) {
        float wgt = hrvl[s0 + i];
        acc0 = fmaf(wgt, prod0[i], acc0);
        acc1 = fmaf(wgt, prod1[i], acc1);
    }
    covs[wave][lane] = acc0;
    covs[wave][64 + lane] = acc1;
    __syncthreads();

    // waves 0,1 finalize rows 0..63 / 64..127
    if (wave < 2) {
        const int row = wave * 64 + lane;
        const int n = nbase + row;
        float cov = covs[0][row] + covs[1][row] + covs[2][row] + covs[3][row];
        float term = 0.0f;
        if (n < N) { float c = coeff[n]; term = (c * c) / cov; }
        double td = (double)term;
        #pragma unroll
        for (int off = 32; off; off >>= 1) td += __shfl_down(td, off);
        if (lane == 0) redd[wave] = td;
    }
    __syncthreads();

    if (tid == 0) {
        partials[blockIdx.x] = redd[0] + redd[1];
        __threadfence();                 // release partial
        int v = atomicAdd(cnt, 1);
        isLast = (v == (int)gridDim.x - 1);
    }
    __syncthreads();

    if (isLast) {                        // last-finishing block reduces all
        __threadfence();                 // acquire
        double s = 0.0;
        for (int i = tid; i < (int)gridDim.x; i += THREADS) s += partials[i];
        #pragma unroll
        for (int off = 32; off; off >>= 1) s += __shfl_down(s, off);
        __shared__ double redf[4];
        if (lane == 0) redf[wave] = s;
        __syncthreads();
        if (tid == 0) out[0] = (float)(redf[0] + redf[1] + redf[2] + redf[3]);
    }
}

extern "C" void kernel_launch(void* const* d_in, const int* in_sizes, int n_in,
                              void* d_out, int out_size, void* d_ws, size_t ws_size,
                              hipStream_t stream) {
    const float* A           = (const float*)d_in[0];  // [N, Q, P]
    const float* coeff       = (const float*)d_in[1];  // [N]
    const float* heads_param = (const float*)d_in[2];  // [S, Q, P]
    const float* hr_param    = (const float*)d_in[3];  // [S]
    const int N = in_sizes[1];
    const int nblocks = (N + BLK_ROWS - 1) / BLK_ROWS;  // 782

    char* ws = (char*)d_ws;
    double* partials = (double*)ws;
    int*   cnt = (int*)(ws + WS_CNT_OFF);
    float* HP  = (float*)(ws + WS_HP_OFF);
    float* hrv = (float*)(ws + WS_HRV_OFF);
    float* out = (float*)d_out;

    const int pre_blocks = (N_S * N_Q + THREADS - 1) / THREADS;  // 13
    precompute_kernel<<<pre_blocks, THREADS, 0, stream>>>(heads_param, hr_param,
                                                          HP, hrv, cnt);
    main_kernel<<<nblocks, THREADS, 0, stream>>>(A, coeff, HP, hrv, partials,
                                                 cnt, out, N);
}